// Round 13
// baseline (1200.193 us; speedup 1.0000x reference)
//
#include <hip/hip_runtime.h>

// ---------------- types / helpers ----------------
typedef unsigned short u16;
typedef unsigned int u32;
typedef unsigned long long u64;
typedef short short8 __attribute__((ext_vector_type(8)));
typedef float f32x4 __attribute__((ext_vector_type(4)));

__device__ __forceinline__ float b2f(u16 u) {
    unsigned x = ((unsigned)u) << 16;
    return __builtin_bit_cast(float, x);
}
__device__ __forceinline__ u16 f2b(float f) {
    unsigned u = __builtin_bit_cast(unsigned, f);
    u += 0x7FFFu + ((u >> 16) & 1u);   // RNE
    return (u16)(u >> 16);
}
__device__ __forceinline__ float lo16f(u32 u) { return __builtin_bit_cast(float, u << 16); }
__device__ __forceinline__ float hi16f(u32 u) { return __builtin_bit_cast(float, u & 0xFFFF0000u); }
__device__ __forceinline__ float sigm(float x) { return 1.f / (1.f + __expf(-x)); }
__device__ __forceinline__ float tanh_(float x) { return 1.f - 2.f / (__expf(2.f * x) + 1.f); }

__device__ __forceinline__ u64 lda(const u64* p) {
    return __hip_atomic_load(p, __ATOMIC_RELAXED, __HIP_MEMORY_SCOPE_AGENT);
}
__device__ __forceinline__ void sta(u64* p, u64 v) {
    __hip_atomic_store(p, v, __ATOMIC_RELAXED, __HIP_MEMORY_SCOPE_AGENT);
}
__device__ __forceinline__ void sta32(u32* p, u32 v) {
    __hip_atomic_store(p, v, __ATOMIC_RELAXED, __HIP_MEMORY_SCOPE_AGENT);
}
__device__ __forceinline__ unsigned ld_flag(const unsigned* p) {
    return __hip_atomic_load(p, __ATOMIC_RELAXED, __HIP_MEMORY_SCOPE_AGENT);
}
__device__ __forceinline__ void st_flag(unsigned* p, unsigned v) {
    __hip_atomic_store(p, v, __ATOMIC_RELAXED, __HIP_MEMORY_SCOPE_AGENT);
}
// agent-coherent 16B load (sc0 sc1), waitcnt fused
__device__ __forceinline__ uint4 ld16c(const void* p) {
    uint4 v;
    asm volatile("global_load_dwordx4 %0, %1, off sc0 sc1\n\ts_waitcnt vmcnt(0)"
                 : "=v"(v) : "v"(p) : "memory");
    return v;
}
// agent-coherent 16B loads, issue-only; pair with wait_vm0()
__device__ __forceinline__ void ld16x4_issue(const void* p0, const void* p1, const void* p2,
                                             const void* p3, uint4& a, uint4& b, uint4& c, uint4& d) {
    asm volatile(
        "global_load_dwordx4 %0, %4, off sc0 sc1\n\t"
        "global_load_dwordx4 %1, %5, off sc0 sc1\n\t"
        "global_load_dwordx4 %2, %6, off sc0 sc1\n\t"
        "global_load_dwordx4 %3, %7, off sc0 sc1"
        : "=v"(a), "=v"(b), "=v"(c), "=v"(d)
        : "v"(p0), "v"(p1), "v"(p2), "v"(p3) : "memory");
}
__device__ __forceinline__ void wait_vm0() {
    asm volatile("s_waitcnt vmcnt(0)" ::: "memory");
}
__device__ __forceinline__ void st16(void* p, uint4 v) {
    u64 lo = ((u64)v.y << 32) | (u64)v.x;
    u64 hi = ((u64)v.w << 32) | (u64)v.z;
    __hip_atomic_store((u64*)p,     lo, __ATOMIC_RELAXED, __HIP_MEMORY_SCOPE_AGENT);
    __hip_atomic_store((u64*)p + 1, hi, __ATOMIC_RELAXED, __HIP_MEMORY_SCOPE_AGENT);
}
__device__ __forceinline__ u64 packf2(float a, float b) {
    return ((u64)__builtin_bit_cast(u32, b) << 32) | (u64)__builtin_bit_cast(u32, a);
}

// ---------------- problem constants ----------------
#define T_STEPS 128
#define BATCH   32
#define KHR     320
#define PADK    328      // hr_lds row pad (bf16 elems); u32 stride 164
#define MEMPAD  68       // mem row stride in floats
#define WKPAD   264      // wkeyT row pad (bf16 elems)

// ---------------- workspace layout (bytes) ----------------
#define WS_BAR      0                         // u32 [32] barrier flags (h barrier + progress)
#define WS_LOSS     128
#define WS_FLAG     160
#define WS_RT       192                       // tagged r: [2][32 wg][16 chunk][2 u64] = 16384
#define WS_HRG      16576                     // u16 [32][320] = 20480 (h region at +64)
#define WS_ZSET     41088                     // memset range end
// normalized fp32 inputs
#define WS_XSF      41216                     // 524288 f32
#define WS_MEM0F    2138368                   // 524288 f32
#define WS_WLF      4235520                   // 655360 f32
#define WS_BLF      6856960                   // 1024 f32
#define WS_WPREF    6861056                   // 32768 f32
#define WS_BPREF    6992128                   // 128 f32
#define WS_WKEYF    6992640                   // 16384 f32
#define WS_WBETAF   7058176                   // 256 f32
#define WS_WTEACHF  7059200                   // 16384 f32
#define WS_WROF     7124736                   // 32768 f32
// derived
#define WS_XW       7255808                   // u32 [4096][512] packed bf16 xW = 8388608
#define WS_WREFF    24033024                  // f32 [64][1024]   = 262144
#define WS_WKT      24295168                  // f32 [256][64]    = 65536
#define WS_WROEFF   24360704                  // f32 [64][128]    = 32768
#define WS_HS       24393472                  // f32 [4096][256]  = 4194304
#define WS_RS       28587776                  // f32 [4096][64]   = 1048576

// ---------------- LDS layout (bytes) ----------------
#define HR_OFF   0         // u16 [32][328]            20992
#define WF_OFF   20992     // u16 [10][4][32][8]       20480
#define WK_OFF   41472     // u16 [64][264]            33792
#define MEM_OFF  75264     // f32 [256][68]            69632
#define Z_OFF    144896    // f32 [32][36]             4608
#define KV_OFF   151552    // f32 [64]                 256
#define KP_OFF   152832    // f32 [4][64]              1024
#define RP_OFF   153856    // f32 [4][64]              1024
#define BR_OFF   154880    // f32 [16]
#define WR_OFF   154944    // f32 [16]
#define SC_OFF   155008    // f32 [16]
#define WB_OFF   155072    // f32 [256]                1024
#define LDS_TOTAL 156736

// ---------------- flag-array grid barrier (32 worker wgs) ----------------
__device__ __forceinline__ void gridbar(unsigned* flags, unsigned phase, int rank) {
    __syncthreads();
    if (threadIdx.x < 64) {
        if (threadIdx.x == 0) st_flag(flags + rank, phase);
        long guard = 0;
        for (;;) {
            unsigned v = ld_flag(flags + (threadIdx.x & 31));
            if (__ballot(v < phase) == 0ull) break;
            if (++guard > 1000000L) break;   // bail instead of hanging
            if (guard > 4) __builtin_amdgcn_s_sleep(1);
        }
    }
    __syncthreads();
}

// ---------------- normalize all inputs to fp32 in ws (dtype probe fused, per-block) ----------------
__global__ void dnc_normalize(const void* s0, const void* s1, const void* s2, const void* s3,
                              const void* s4, const void* s5, const void* s6, const void* s7,
                              const void* s8, const void* s9, char* __restrict__ ws) {
    __shared__ int cnt;
    if (threadIdx.x == 0) cnt = 0;
    __syncthreads();
    {   // deterministic local probe: every block computes the same flag
        const u16* xs_u16 = (const u16*)s0;
        int c = 0;
        for (int i = threadIdx.x; i < 1024; i += 256) {
            int e = (xs_u16[i] >> 7) & 0xFF;
            if (e >= 96 && e <= 135) c++;
        }
        atomicAdd(&cnt, c);
    }
    __syncthreads();
    const int bf = (cnt > 820) ? 1 : 0;   // 1 = bf16
    if (blockIdx.x == 0 && threadIdx.x == 0) *(int*)(ws + WS_FLAG) = bf;
    const void* srcs[10] = {s0, s1, s2, s3, s4, s5, s6, s7, s8, s9};
    const int sizes[10] = {524288, 524288, 655360, 1024, 32768, 128, 16384, 256, 16384, 32768};
    const int bases[10] = {WS_XSF, WS_MEM0F, WS_WLF, WS_BLF, WS_WPREF, WS_BPREF,
                           WS_WKEYF, WS_WBETAF, WS_WTEACHF, WS_WROF};
    const int gt = blockIdx.x * 256 + threadIdx.x, gs = gridDim.x * 256;
    for (int s = 0; s < 10; ++s) {
        float* dst = (float*)(ws + bases[s]);
        const int n = sizes[s];
        if (bf) {
            const u16* p = (const u16*)srcs[s];
            for (int i = gt; i < n; i += gs) dst[i] = b2f(p[i]);
        } else {
            const float* p = (const float*)srcs[s];
            for (int i = gt; i < n; i += gs) dst[i] = p[i];
        }
    }
}

// ---------------- prologue: xW GEMM (packed bf16 out) + weight folds ----------------
__global__ void dnc_prologue(char* __restrict__ ws) {
    extern __shared__ float xls[];   // [128][129]
    const float* XSF     = (const float*)(ws + WS_XSF);
    const float* WLF     = (const float*)(ws + WS_WLF);
    const float* BLF     = (const float*)(ws + WS_BLF);
    const float* WKEYF   = (const float*)(ws + WS_WKEYF);
    const float* WTEACHF = (const float*)(ws + WS_WTEACHF);
    const float* WROF    = (const float*)(ws + WS_WROF);
    u32*   xW  = (u32*)(ws + WS_XW);
    float* WrE = (float*)(ws + WS_WREFF);
    float* Wkt = (float*)(ws + WS_WKT);
    float* Wre = (float*)(ws + WS_WROEFF);
    const int wg = blockIdx.x, tid = threadIdx.x;
    if (wg < 512) {
        const int rb = wg >> 4, cb = wg & 15;   // 32 row-blocks x 16 col-blocks (128x64 tiles)
        const float4* xsrc = (const float4*)(XSF + (size_t)rb * 16384);
        for (int i = tid; i < 4096; i += 256) {
            float4 v = xsrc[i];
            int row = i >> 5, c4 = (i & 31) * 4;
            float* d = xls + row * 129 + c4;
            d[0] = v.x; d[1] = v.y; d[2] = v.z; d[3] = v.w;
        }
        __syncthreads();
        const int tr = tid >> 4, tc = tid & 15;
        const int c0 = cb * 64 + tc * 4;
        float acc[8][4];
#pragma unroll
        for (int rr = 0; rr < 8; ++rr) {
            acc[rr][0] = BLF[c0]; acc[rr][1] = BLF[c0 + 1];
            acc[rr][2] = BLF[c0 + 2]; acc[rr][3] = BLF[c0 + 3];
        }
        for (int k = 0; k < 128; ++k) {
            float4 w4 = *(const float4*)(WLF + (size_t)k * 1024 + c0);
#pragma unroll
            for (int rr = 0; rr < 8; ++rr) {
                float xv = xls[(tr * 8 + rr) * 129 + k];
                acc[rr][0] += xv * w4.x; acc[rr][1] += xv * w4.y;
                acc[rr][2] += xv * w4.z; acc[rr][3] += xv * w4.w;
            }
        }
#pragma unroll
        for (int rr = 0; rr < 8; ++rr) {
            size_t o = (size_t)(rb * 128 + tr * 8 + rr) * 512 + cb * 32 + tc * 2;
            u32 p0 = (u32)f2b(acc[rr][0]) | ((u32)f2b(acc[rr][1]) << 16);
            u32 p1 = (u32)f2b(acc[rr][2]) | ((u32)f2b(acc[rr][3]) << 16);
            *(uint2*)(xW + o) = make_uint2(p0, p1);
        }
    } else if (wg < 576) {
        const int m = wg - 512;
        const int c = tid * 4;
#pragma unroll
        for (int e = 0; e < 4; ++e) {
            float s = 0.f;
#pragma unroll
            for (int rr = 0; rr < 4; ++rr) s += WLF[(size_t)(128 + 4 * m + rr) * 1024 + c + e];
            WrE[m * 1024 + c + e] = s;
        }
    } else if (wg < 592) {
        const int i = (wg - 576) * 1024 + tid * 4;
#pragma unroll
        for (int e = 0; e < 4; ++e) Wkt[i + e] = WKEYF[i + e] - WTEACHF[i + e];
    } else if (wg < 600) {
        const int i = (wg - 592) * 1024 + tid * 4;
#pragma unroll
        for (int e = 0; e < 4; ++e) {
            int m = (i + e) >> 7, c = (i + e) & 127;
            float s = 0.f;
#pragma unroll
            for (int rr = 0; rr < 4; ++rr) s += WROF[(4 * m + rr) * 128 + c];
            Wre[i + e] = s;
        }
    }
}

// ---------------- main: 32 worker wgs + 224 epilogue wgs (idle CUs) ----------------
// Workers: 1 barrier/step (h); r via tagged dataflow with full-update shadow.
// Epilogue wgs: poll the barrier flags (flags >= t+2 => Hs(t)/Rs(t) complete at
// the coherence point, since stores drain before each flag store) and process
// 8-row output chunks concurrently with the recurrence. Workers store flag 129
// after the loop to cover t=127.
__global__ __launch_bounds__(256, 1) void dnc_main(char* __restrict__ ws, void* __restrict__ outv) {
    extern __shared__ char smem[];
    const int tid = threadIdx.x;
    unsigned* flags = (unsigned*)(ws + WS_BAR);

    if (blockIdx.x >= 32) {
        // ================= epilogue role =================
        float* hs8 = (float*)smem;                 // [2048] = 8 rows x 256
        float* rs8 = (float*)(smem + 8192);        // [512]  = 8 rows x 64
        float* lacc = (float*)(smem + 10240);
        const float* WktF  = (const float*)(ws + WS_WKT);
        const float* WreF  = (const float*)(ws + WS_WROEFF);
        const float* WpreF = (const float*)(ws + WS_WPREF);
        const float* bpreF = (const float*)(ws + WS_BPREF);
        float* lossacc = (float*)(ws + WS_LOSS);
        const int bf = *(const int*)(ws + WS_FLAG);
        for (int chunk = (int)blockIdx.x - 32; chunk < 512; chunk += 224) {
            const int t = chunk >> 2;
            const unsigned need = (t < 127) ? (unsigned)(t + 2) : 129u;
            if (tid < 64) {
                long g = 0;
                for (;;) {
                    unsigned v = ld_flag(flags + (tid & 31));
                    if (__ballot(v < need) == 0ull) break;
                    if (++g > 30000000L) break;   // bail instead of hanging
                    __builtin_amdgcn_s_sleep(8);
                }
            }
            if (tid == 0) lacc[0] = 0.f;
            __syncthreads();
            const size_t r0 = (size_t)chunk * 8;
            for (int i = tid; i < 512; i += 256)
                ((uint4*)hs8)[i] = ld16c((const char*)ws + WS_HS + (r0 * 256 + (size_t)i * 4) * 4);
            if (tid < 128)
                ((uint4*)rs8)[tid] = ld16c((const char*)ws + WS_RS + (r0 * 64 + (size_t)tid * 4) * 4);
            __syncthreads();
            // ys
            {
                const int rl = tid >> 5, c0 = (tid & 31) * 4;
                float a0 = bpreF[c0], a1 = bpreF[c0 + 1], a2 = bpreF[c0 + 2], a3 = bpreF[c0 + 3];
                for (int k = 0; k < 256; ++k) {
                    float hv = hs8[rl * 256 + k];
                    float4 w4 = *(const float4*)(WpreF + k * 128 + c0);
                    a0 += hv * w4.x; a1 += hv * w4.y; a2 += hv * w4.z; a3 += hv * w4.w;
                }
                for (int m = 0; m < 64; ++m) {
                    float rv = rs8[rl * 64 + m];
                    float4 w4 = *(const float4*)(WreF + m * 128 + c0);
                    a0 += rv * w4.x; a1 += rv * w4.y; a2 += rv * w4.z; a3 += rv * w4.w;
                }
                size_t o = (r0 + rl) * 128 + c0;
                if (bf) {
                    u16* out = (u16*)outv;
                    out[o] = f2b(a0); out[o + 1] = f2b(a1); out[o + 2] = f2b(a2); out[o + 3] = f2b(a3);
                } else {
                    float* out = (float*)outv;
                    out[o] = a0; out[o + 1] = a1; out[o + 2] = a2; out[o + 3] = a3;
                }
            }
            // loss partials: sum (h @ (Wkey - Wteach))^2
            {
                const int rl = tid >> 5, m0 = (tid & 31) * 2;
                float d0 = 0.f, d1 = 0.f;
                for (int k = 0; k < 256; ++k) {
                    float hv = hs8[rl * 256 + k];
                    d0 += hv * WktF[k * 64 + m0];
                    d1 += hv * WktF[k * 64 + m0 + 1];
                }
                float p = d0 * d0 + d1 * d1;
#pragma unroll
                for (int off = 32; off > 0; off >>= 1) p += __shfl_xor(p, off, 64);
                if ((tid & 63) == 0) atomicAdd(lacc, p);
            }
            __syncthreads();
            if (tid == 0) atomicAdd(lossacc, lacc[0]);
        }
        return;
    }

    // ================= worker role =================
    u16*   hr_lds = (u16*)(smem + HR_OFF);
    u16*   wfrag  = (u16*)(smem + WF_OFF);
    u16*   wkeyT  = (u16*)(smem + WK_OFF);
    float* memA   = (float*)(smem + MEM_OFF);
    float* z_lds  = (float*)(smem + Z_OFF);
    float* kv     = (float*)(smem + KV_OFF);
    float* kpart  = (float*)(smem + KP_OFF);
    float* rp     = (float*)(smem + RP_OFF);
    float* bred   = (float*)(smem + BR_OFF);
    float* wred   = (float*)(smem + WR_OFF);
    float* sc     = (float*)(smem + SC_OFF);
    float* wbF    = (float*)(smem + WB_OFF);

    const int wg   = blockIdx.x;     // col-slice id AND batch id (0..31)
    const int lane = tid & 63;
    const int wid  = tid >> 6;

    u64* rT  = (u64*)(ws + WS_RT);      // [2][32 wg][16 chunk][2 u64]
    u16* hrg = (u16*)(ws + WS_HRG);     // [32][320] bf16 (h at +64)
    const u32*   xWP     = (const u32*)(ws + WS_XW);
    const float* WrEffF  = (const float*)(ws + WS_WREFF);
    const float* WLF     = (const float*)(ws + WS_WLF);
    const float* WKEYF   = (const float*)(ws + WS_WKEYF);
    const float* WBETAF  = (const float*)(ws + WS_WBETAF);
    const float* MEM0F   = (const float*)(ws + WS_MEM0F);
    u32* HsA = (u32*)(ws + WS_HS);
    float* RsF = (float*)(ws + WS_RS);

    // ---- one-time LDS init ----
    for (int i = tid; i < 32 * PADK; i += 256) hr_lds[i] = 0;   // h(-1)=0, r(-1)=0
    for (int idx = tid; idx < 10240; idx += 256) {
        int k = idx >> 5, c = idx & 31;
        int kt = k >> 5, q = (k >> 3) & 3, j = k & 7;
        int gcol = (c >> 3) * 256 + wg * 8 + (c & 7);
        float v = (k < 64) ? WrEffF[k * 1024 + gcol]
                           : WLF[(size_t)(384 + (k - 64)) * 1024 + gcol];
        wfrag[((kt * 4 + q) * 32 + c) * 8 + j] = f2b(v);
    }
    for (int i = tid; i < 256 * 64; i += 256) {   // wkeyT[m][k] = Wkey[k][m] (bf16)
        int k = i >> 6, m = i & 63;
        wkeyT[m * WKPAD + k] = f2b(WKEYF[i]);
    }
    wbF[tid] = WBETAF[tid];
    for (int i = tid; i < 256 * 64; i += 256) {   // mem state fp32
        int n = i >> 6, m = i & 63;
        memA[n * MEMPAD + m] = MEM0F[wg * 16384 + i];
    }
    __syncthreads();

    const int bt = wid & 1, ct = wid >> 1;   // MFMA tile assignment
    const int fm = lane & 15, fq = lane >> 4;
    const int pb = tid >> 3, pu = tid & 7;   // batch / slice-unit for staging & pointwise
    float c_reg = 0.f;                       // LSTM cell state for (pb, unit wg*8+pu)

    // xW gates for t=0 (packed bf16); h@Wh accumulator for t=0 is 0
    float xg0, xg1, xg2, xg3;
    {
        const size_t xb = (size_t)pb * 512 + wg * 4 + (pu >> 1);
        u32 u0 = xWP[xb], u1 = xWP[xb + 128], u2 = xWP[xb + 256], u3 = xWP[xb + 384];
        if (pu & 1) { xg0 = hi16f(u0); xg1 = hi16f(u1); xg2 = hi16f(u2); xg3 = hi16f(u3); }
        else        { xg0 = lo16f(u0); xg1 = lo16f(u1); xg2 = lo16f(u2); xg3 = lo16f(u3); }
    }
    f32x4 hWacc = {0.f, 0.f, 0.f, 0.f};

    for (int t = 0; t < T_STEPS; ++t) {
        // ================= phase A =================
        // poll r(t-1): buffer (t+1)&1, tag t. Long publish shadow -> first-try.
        {
            const u64* rch = rT + (size_t)((((t + 1) & 1) * 32 + pb) * 16 + 2 * pu) * 2;
            const u32 want = (u32)t;
            u64 v0, v1, v2, v3;
            long guard = 0;
            for (;;) {
                v0 = lda(rch); v1 = lda(rch + 1); v2 = lda(rch + 2); v3 = lda(rch + 3);
                bool ok = ((u32)v0 == want) && ((u32)(v1 >> 32) == want) &&
                          ((u32)v2 == want) && ((u32)(v3 >> 32) == want);
                if (ok) break;
                if (++guard > 2000000L) break;   // bail instead of hanging
                if (guard > 4) __builtin_amdgcn_s_sleep(1);
            }
            u32* dst = (u32*)hr_lds + pb * 164 + 4 * pu;
            dst[0] = (u32)(v0 >> 32); dst[1] = (u32)v1;
            dst[2] = (u32)(v2 >> 32); dst[3] = (u32)v3;
        }
        __syncthreads();

        // rW MFMA (kt=0,1) accumulating onto carried h@Wh
        f32x4 acc = hWacc;
#pragma unroll
        for (int kt = 0; kt < 2; ++kt) {
            short8 a = *(const short8*)(hr_lds + (bt * 16 + fm) * PADK + kt * 32 + fq * 8);
            short8 b = *(const short8*)(wfrag + ((kt * 4 + fq) * 32 + ct * 16 + fm) * 8);
            acc = __builtin_amdgcn_mfma_f32_16x16x32_bf16(a, b, acc, 0, 0, 0);
        }
#pragma unroll
        for (int r = 0; r < 4; ++r) {
            int bb = bt * 16 + fq * 4 + r;        // C/D: row = quad*4+reg
            int cc = ct * 16 + fm;                //       col = lane&15
            z_lds[bb * 36 + cc] = acc[r];
        }
        __syncthreads();

        // LSTM pointwise for hidden units [8*wg, 8*wg+8), all batches
        float hn;
        {
            float iv = z_lds[pb * 36 + pu]      + xg0;
            float fv = z_lds[pb * 36 + 8 + pu]  + xg1;
            float gv = z_lds[pb * 36 + 16 + pu] + xg2;
            float ov = z_lds[pb * 36 + 24 + pu] + xg3;
            float cn = sigm(fv) * c_reg + sigm(iv) * tanh_(gv);
            hn = sigm(ov) * tanh_(cn);
            c_reg = cn;
            sta32(HsA + (size_t)(t * BATCH + pb) * 256 + wg * 8 + pu,
                  __builtin_bit_cast(u32, hn));   // epilogue-visible
        }
        // gather this batch's 8 h values via intra-wave shuffles; pu==0 stores 16B
        {
            u32 hbits = (u32)f2b(hn);
            int base = lane & 56;
            u32 w0 = __shfl(hbits, base + 0, 64) | (__shfl(hbits, base + 1, 64) << 16);
            u32 w1 = __shfl(hbits, base + 2, 64) | (__shfl(hbits, base + 3, 64) << 16);
            u32 w2 = __shfl(hbits, base + 4, 64) | (__shfl(hbits, base + 5, 64) << 16);
            u32 w3 = __shfl(hbits, base + 6, 64) | (__shfl(hbits, base + 7, 64) << 16);
            if ((lane & 7) == 0) {
                uint4 hv; hv.x = w0; hv.y = w1; hv.z = w2; hv.w = w3;
                st16(hrg + pb * KHR + 64 + wg * 8, hv);
            }
        }
        gridbar(flags, (unsigned)(t + 1), wg);

        // ================= phase B =================
        // issue h(t) prefetch (16 KB total), no waitcnt yet
        uint4 ha, hb4, hc, hd;
        {
            const u16* src = hrg + pb * KHR + 64 + pu * 32;
            ld16x4_issue(src, src + 8, src + 16, src + 24, ha, hb4, hc, hd);
        }
        // xW gates for t+1 (plain cached loads, drain at wait_vm0)
        {
            int tn = (t + 1 < T_STEPS) ? t + 1 : 127;
            const size_t xb = (size_t)(tn * BATCH + pb) * 512 + wg * 4 + (pu >> 1);
            u32 u0 = xWP[xb], u1 = xWP[xb + 128], u2 = xWP[xb + 256], u3 = xWP[xb + 384];
            if (pu & 1) { xg0 = hi16f(u0); xg1 = hi16f(u1); xg2 = hi16f(u2); xg3 = hi16f(u3); }
            else        { xg0 = lo16f(u0); xg1 = lo16f(u1); xg2 = lo16f(u2); xg3 = lo16f(u3); }
        }
        // h-independent work while loads fly: ||mem_n||^2 (mem_old)
        float nr2 = 0.f;
        {
            const float4* mrow = (const float4*)(memA + tid * MEMPAD);
#pragma unroll
            for (int i = 0; i < 16; ++i) {
                float4 m4 = mrow[i];
                nr2 += m4.x * m4.x + m4.y * m4.y + m4.z * m4.z + m4.w * m4.w;
            }
        }
        wait_vm0();
        {
            u16* dst = hr_lds + pb * PADK + 64 + pu * 32;
            *(uint4*)(dst)      = ha;
            *(uint4*)(dst + 8)  = hb4;
            *(uint4*)(dst + 16) = hc;
            *(uint4*)(dst + 24) = hd;
        }
        __syncthreads();

        // hW MFMA (kt=2..9) -> fresh accumulator carried to phase A of t+1
        {
            f32x4 hz = {0.f, 0.f, 0.f, 0.f};
#pragma unroll
            for (int kt = 2; kt < 10; ++kt) {
                short8 a = *(const short8*)(hr_lds + (bt * 16 + fm) * PADK + kt * 32 + fq * 8);
                short8 b = *(const short8*)(wfrag + ((kt * 4 + fq) * 32 + ct * 16 + fm) * 8);
                hz = __builtin_amdgcn_mfma_f32_16x16x32_bf16(a, b, hz, 0, 0, 0);
            }
            hWacc = hz;
        }

        // M phase: this wg owns batch b = wg; h_b in hr_lds[wg]
        const u16* hrow = hr_lds + wg * PADK + 64;
        {
            float a = 0.f;
#pragma unroll
            for (int i = 0; i < 8; ++i) {
                short8 w8 = *(const short8*)(wkeyT + lane * WKPAD + wid * 64 + i * 8);
                short8 h8 = *(const short8*)(hrow + wid * 64 + i * 8);
#pragma unroll
                for (int e = 0; e < 8; ++e)
                    a += b2f((u16)h8[e]) * b2f((u16)w8[e]);
            }
            kpart[wid * 64 + lane] = a;
        }
        {
            float bp = b2f(hrow[tid]) * wbF[tid];
#pragma unroll
            for (int off = 32; off > 0; off >>= 1) bp += __shfl_xor(bp, off, 64);
            if (lane == 0) bred[wid] = bp;
        }
        __syncthreads();
        if (tid < 64) {   // finalize k, ||k||
            float kk = kpart[tid] + kpart[64 + tid] + kpart[128 + tid] + kpart[192 + tid];
            kv[tid] = kk;
            float k2 = kk * kk;
#pragma unroll
            for (int off = 32; off > 0; off >>= 1) k2 += __shfl_xor(k2, off, 64);
            if (tid == 0) sc[1] = sqrtf(k2);
        } else if (tid == 64) {   // beta = softplus
            float zb = bred[0] + bred[1] + bred[2] + bred[3];
            sc[0] = logf(1.f + __expf(zb));
        }
        __syncthreads();
        const float beta = sc[0], knorm = sc[1];

        // num pass (nr2 precomputed): thread = mem row, on mem_old
        float num = 0.f;
        {
            const float4* mrow = (const float4*)(memA + tid * MEMPAD);
            const float4* k4p  = (const float4*)kv;
#pragma unroll
            for (int i = 0; i < 16; ++i) {
                float4 m4 = mrow[i], k4 = k4p[i];
                num += m4.x * k4.x + m4.y * k4.y + m4.z * k4.z + m4.w * k4.w;
            }
        }
        float den = fmaxf(sqrtf(nr2) * knorm, 1e-8f);
        float s   = beta * (num / den);
        // per-wave max + sumexp + sumexp^2 (fused ||w||^2), then combine
        float wm = s;
#pragma unroll
        for (int off = 32; off > 0; off >>= 1) wm = fmaxf(wm, __shfl_xor(wm, off, 64));
        float ev = __expf(s - wm);
        float wsum = ev, wsumsq = ev * ev;
#pragma unroll
        for (int off = 32; off > 0; off >>= 1) {
            wsum   += __shfl_xor(wsum, off, 64);
            wsumsq += __shfl_xor(wsumsq, off, 64);
        }
        if (lane == 0) { wred[wid] = wm; wred[4 + wid] = wsum; wred[8 + wid] = wsumsq; }
        __syncthreads();
        float gm = fmaxf(fmaxf(wred[0], wred[1]), fmaxf(wred[2], wred[3]));
        float e0 = __expf(wred[0] - gm), e1 = __expf(wred[1] - gm);
        float e2 = __expf(wred[2] - gm), e3 = __expf(wred[3] - gm);
        float gsum  = wred[4] * e0 + wred[5] * e1 + wred[6] * e2 + wred[7] * e3;
        float gsumq = wred[8] * e0 * e0 + wred[9] * e1 * e1
                    + wred[10] * e2 * e2 + wred[11] * e3 * e3;
        float w   = __expf(s - gm) / gsum;          // weight for row tid
        float wsq = gsumq / (gsum * gsum);          // ||w||^2

        // READ pass on mem_old: w lives in-wave -> shuffles
        {
            const int lm = lane & 15, q = lane >> 4;
            float r0 = 0.f, r1 = 0.f, r2 = 0.f, r3 = 0.f;
#pragma unroll
            for (int i = 0; i < 16; ++i) {
                float wn = __shfl(w, i * 4 + q, 64);
                float4 m4 = *(const float4*)(memA + (wid * 64 + i * 4 + q) * MEMPAD + 4 * lm);
                r0 += wn * m4.x; r1 += wn * m4.y; r2 += wn * m4.z; r3 += wn * m4.w;
            }
            r0 += __shfl_xor(r0, 16, 64); r0 += __shfl_xor(r0, 32, 64);
            r1 += __shfl_xor(r1, 16, 64); r1 += __shfl_xor(r1, 32, 64);
            r2 += __shfl_xor(r2, 16, 64); r2 += __shfl_xor(r2, 32, 64);
            r3 += __shfl_xor(r3, 16, 64); r3 += __shfl_xor(r3, 32, 64);
            if (q == 0) {
                rp[wid * 64 + 4 * lm + 0] = r0;
                rp[wid * 64 + 4 * lm + 1] = r1;
                rp[wid * 64 + 4 * lm + 2] = r2;
                rp[wid * 64 + 4 * lm + 3] = r3;
            }
        }
        __syncthreads();
        // tid<16: finalize 4 r-units each, publish tagged + Rs (coherent), pre-update
        if (tid < 16) {
            float rd0 = rp[4 * tid]     + rp[64 + 4 * tid]     + rp[128 + 4 * tid]     + rp[192 + 4 * tid]     + wsq * kv[4 * tid];
            float rd1 = rp[4 * tid + 1] + rp[64 + 4 * tid + 1] + rp[128 + 4 * tid + 1] + rp[192 + 4 * tid + 1] + wsq * kv[4 * tid + 1];
            float rd2 = rp[4 * tid + 2] + rp[64 + 4 * tid + 2] + rp[128 + 4 * tid + 2] + rp[192 + 4 * tid + 2] + wsq * kv[4 * tid + 2];
            float rd3 = rp[4 * tid + 3] + rp[64 + 4 * tid + 3] + rp[128 + 4 * tid + 3] + rp[192 + 4 * tid + 3] + wsq * kv[4 * tid + 3];
            u32 w0 = (u32)f2b(rd0) | ((u32)f2b(rd1) << 16);
            u32 w1 = (u32)f2b(rd2) | ((u32)f2b(rd3) << 16);
            u64* dstc = rT + (size_t)(((t & 1) * 32 + wg) * 16 + tid) * 2;
            const u64 tag = (u64)(u32)(t + 1);
            sta(dstc,     ((u64)w0 << 32) | tag);
            sta(dstc + 1, (tag << 32) | w1);
            u64* rdst = (u64*)(RsF + (size_t)(t * BATCH + wg) * 64 + 4 * tid);
            sta(rdst,     packf2(rd0, rd1));   // epilogue-visible
            sta(rdst + 1, packf2(rd2, rd3));
        }
        // mem UPDATE pass — off the critical path (covers r's flight to the LLC)
        {
            const int lm = lane & 15, q = lane >> 4;
            float4 k4 = ((const float4*)kv)[lm];
#pragma unroll
            for (int i = 0; i < 16; ++i) {
                float wn = __shfl(w, i * 4 + q, 64);
                float4* mp = (float4*)(memA + (wid * 64 + i * 4 + q) * MEMPAD + 4 * lm);
                float4 m4 = *mp;
                m4.x += wn * k4.x; m4.y += wn * k4.y; m4.z += wn * k4.z; m4.w += wn * k4.w;
                *mp = m4;
            }
        }
        // no barrier2: next step's r-poll + barrier1 bound the skew
    }
    // signal Rs(127)/Hs(127) complete for epilogue wgs
    __syncthreads();
    if (tid == 0) st_flag(flags + wg, 129u);
}

__global__ void dnc_loss_fin(const char* __restrict__ ws, void* __restrict__ outv) {
    if (threadIdx.x == 0 && blockIdx.x == 0) {
        float l = *(const float*)(ws + WS_LOSS) * (1.f / 2048.f);
        if (*(const int*)(ws + WS_FLAG)) ((u16*)outv)[524288] = f2b(l);
        else                             ((float*)outv)[524288] = l;
    }
}

// ---------------- launch ----------------
extern "C" void kernel_launch(void* const* d_in, const int* in_sizes, int n_in,
                              void* d_out, int out_size, void* d_ws, size_t ws_size,
                              hipStream_t stream) {
    char* ws = (char*)d_ws;
    hipMemsetAsync(d_ws, 0, WS_ZSET, stream);   // flags, rT tags, loss, dtype flag, hrg
    dnc_normalize<<<512, 256, 0, stream>>>(d_in[0], d_in[1], d_in[2], d_in[3], d_in[4],
                                           d_in[5], d_in[6], d_in[7], d_in[8], d_in[9], ws);
    (void)hipFuncSetAttribute((const void*)dnc_prologue,
                              hipFuncAttributeMaxDynamicSharedMemorySize, 128 * 129 * 4);
    dnc_prologue<<<600, 256, 128 * 129 * 4, stream>>>(ws);
    (void)hipFuncSetAttribute((const void*)dnc_main,
                              hipFuncAttributeMaxDynamicSharedMemorySize, LDS_TOTAL);
    dnc_main<<<256, 256, LDS_TOTAL, stream>>>(ws, d_out);
    dnc_loss_fin<<<1, 64, 0, stream>>>(ws, d_out);
}

// Round 14
// 1052.702 us; speedup vs baseline: 1.1401x; 1.1401x over previous
//
#include <hip/hip_runtime.h>

// ---------------- types / helpers ----------------
typedef unsigned short u16;
typedef unsigned int u32;
typedef unsigned long long u64;
typedef short short8 __attribute__((ext_vector_type(8)));
typedef float f32x4 __attribute__((ext_vector_type(4)));

__device__ __forceinline__ float b2f(u16 u) {
    unsigned x = ((unsigned)u) << 16;
    return __builtin_bit_cast(float, x);
}
__device__ __forceinline__ u16 f2b(float f) {
    unsigned u = __builtin_bit_cast(unsigned, f);
    u += 0x7FFFu + ((u >> 16) & 1u);   // RNE
    return (u16)(u >> 16);
}
__device__ __forceinline__ float lo16f(u32 u) { return __builtin_bit_cast(float, u << 16); }
__device__ __forceinline__ float hi16f(u32 u) { return __builtin_bit_cast(float, u & 0xFFFF0000u); }
__device__ __forceinline__ float sigm(float x) { return 1.f / (1.f + __expf(-x)); }
__device__ __forceinline__ float tanh_(float x) { return 1.f - 2.f / (__expf(2.f * x) + 1.f); }

__device__ __forceinline__ u64 lda(const u64* p) {
    return __hip_atomic_load(p, __ATOMIC_RELAXED, __HIP_MEMORY_SCOPE_AGENT);
}
__device__ __forceinline__ void sta(u64* p, u64 v) {
    __hip_atomic_store(p, v, __ATOMIC_RELAXED, __HIP_MEMORY_SCOPE_AGENT);
}
__device__ __forceinline__ unsigned ld_flag(const unsigned* p) {
    return __hip_atomic_load(p, __ATOMIC_RELAXED, __HIP_MEMORY_SCOPE_AGENT);
}
__device__ __forceinline__ void st_flag(unsigned* p, unsigned v) {
    __hip_atomic_store(p, v, __ATOMIC_RELAXED, __HIP_MEMORY_SCOPE_AGENT);
}
// agent-coherent 16B loads, issue-only; pair with wait_vm0()
__device__ __forceinline__ void ld16x4_issue(const void* p0, const void* p1, const void* p2,
                                             const void* p3, uint4& a, uint4& b, uint4& c, uint4& d) {
    asm volatile(
        "global_load_dwordx4 %0, %4, off sc0 sc1\n\t"
        "global_load_dwordx4 %1, %5, off sc0 sc1\n\t"
        "global_load_dwordx4 %2, %6, off sc0 sc1\n\t"
        "global_load_dwordx4 %3, %7, off sc0 sc1"
        : "=v"(a), "=v"(b), "=v"(c), "=v"(d)
        : "v"(p0), "v"(p1), "v"(p2), "v"(p3) : "memory");
}
__device__ __forceinline__ void wait_vm0() {
    asm volatile("s_waitcnt vmcnt(0)" ::: "memory");
}
__device__ __forceinline__ void st16(void* p, uint4 v) {
    u64 lo = ((u64)v.y << 32) | (u64)v.x;
    u64 hi = ((u64)v.w << 32) | (u64)v.z;
    __hip_atomic_store((u64*)p,     lo, __ATOMIC_RELAXED, __HIP_MEMORY_SCOPE_AGENT);
    __hip_atomic_store((u64*)p + 1, hi, __ATOMIC_RELAXED, __HIP_MEMORY_SCOPE_AGENT);
}

// ---------------- problem constants ----------------
#define T_STEPS 128
#define BATCH   32
#define KHR     320
#define PADK    328      // hr_lds row pad (bf16 elems); u32 stride 164
#define MEMPAD  68       // mem row stride in floats
#define WKPAD   264      // wkeyT row pad (bf16 elems)

// ---------------- workspace layout (bytes) ----------------
#define WS_BAR      0                         // u32 [32] barrier flags (h barrier)
#define WS_LOSS     128
#define WS_FLAG     160
#define WS_RT       192                       // tagged r: [2][32 wg][16 chunk][2 u64] = 16384
#define WS_HRG      16576                     // u16 [32][320] = 20480 (h region at +64)
#define WS_ZSET     41088                     // memset range end
// normalized fp32 inputs
#define WS_XSF      41216                     // 524288 f32
#define WS_MEM0F    2138368                   // 524288 f32
#define WS_WLF      4235520                   // 655360 f32
#define WS_BLF      6856960                   // 1024 f32
#define WS_WPREF    6861056                   // 32768 f32
#define WS_BPREF    6992128                   // 128 f32
#define WS_WKEYF    6992640                   // 16384 f32
#define WS_WBETAF   7058176                   // 256 f32
#define WS_WTEACHF  7059200                   // 16384 f32
#define WS_WROF     7124736                   // 32768 f32
// derived
#define WS_XW       7255808                   // u32 [4096][512] packed bf16 xW = 8388608
#define WS_WREFF    24033024                  // f32 [64][1024]   = 262144
#define WS_WKT      24295168                  // f32 [256][64]    = 65536
#define WS_WROEFF   24360704                  // f32 [64][128]    = 32768
#define WS_HS       24393472                  // f32 [4096][256]  = 4194304
#define WS_RS       28587776                  // f32 [4096][64]   = 1048576

// ---------------- LDS layout (bytes) ----------------
#define HR_OFF   0         // u16 [32][328]            20992
#define WF_OFF   20992     // u16 [10][4][32][8]       20480
#define WK_OFF   41472     // u16 [64][264]            33792
#define MEM_OFF  75264     // f32 [256][68]            69632
#define Z_OFF    144896    // f32 [32][36]             4608
#define KV_OFF   151552    // f32 [64]                 256
#define KP_OFF   152832    // f32 [4][64]              1024
#define RP_OFF   153856    // f32 [4][64]              1024
#define BR_OFF   154880    // f32 [16]
#define WR_OFF   154944    // f32 [16]
#define SC_OFF   155008    // f32 [16]
#define WB_OFF   155072    // f32 [256]                1024
#define LDS_TOTAL 156736

// ---------------- flag-array grid barrier (32 wgs) — h exchange only ----------------
__device__ __forceinline__ void gridbar(unsigned* flags, unsigned phase, int rank) {
    __syncthreads();
    if (threadIdx.x < 64) {
        if (threadIdx.x == 0) st_flag(flags + rank, phase);
        long guard = 0;
        for (;;) {
            unsigned v = ld_flag(flags + (threadIdx.x & 31));
            if (__ballot(v < phase) == 0ull) break;
            if (++guard > 1000000L) break;   // bail instead of hanging
            if (guard > 4) __builtin_amdgcn_s_sleep(1);
        }
    }
    __syncthreads();
}

// ---------------- normalize all inputs to fp32 in ws (dtype probe fused, per-block) ----------------
__global__ void dnc_normalize(const void* s0, const void* s1, const void* s2, const void* s3,
                              const void* s4, const void* s5, const void* s6, const void* s7,
                              const void* s8, const void* s9, char* __restrict__ ws) {
    __shared__ int cnt;
    if (threadIdx.x == 0) cnt = 0;
    __syncthreads();
    {   // deterministic local probe: every block computes the same flag
        const u16* xs_u16 = (const u16*)s0;
        int c = 0;
        for (int i = threadIdx.x; i < 1024; i += 256) {
            int e = (xs_u16[i] >> 7) & 0xFF;
            if (e >= 96 && e <= 135) c++;
        }
        atomicAdd(&cnt, c);
    }
    __syncthreads();
    const int bf = (cnt > 820) ? 1 : 0;   // 1 = bf16
    if (blockIdx.x == 0 && threadIdx.x == 0) *(int*)(ws + WS_FLAG) = bf;
    const void* srcs[10] = {s0, s1, s2, s3, s4, s5, s6, s7, s8, s9};
    const int sizes[10] = {524288, 524288, 655360, 1024, 32768, 128, 16384, 256, 16384, 32768};
    const int bases[10] = {WS_XSF, WS_MEM0F, WS_WLF, WS_BLF, WS_WPREF, WS_BPREF,
                           WS_WKEYF, WS_WBETAF, WS_WTEACHF, WS_WROF};
    const int gt = blockIdx.x * 256 + threadIdx.x, gs = gridDim.x * 256;
    for (int s = 0; s < 10; ++s) {
        float* dst = (float*)(ws + bases[s]);
        const int n = sizes[s];
        if (bf) {
            const u16* p = (const u16*)srcs[s];
            for (int i = gt; i < n; i += gs) dst[i] = b2f(p[i]);
        } else {
            const float* p = (const float*)srcs[s];
            for (int i = gt; i < n; i += gs) dst[i] = p[i];
        }
    }
}

// ---------------- prologue: xW GEMM (packed bf16 out) + weight folds ----------------
__global__ void dnc_prologue(char* __restrict__ ws) {
    extern __shared__ float xls[];   // [128][129]
    const float* XSF     = (const float*)(ws + WS_XSF);
    const float* WLF     = (const float*)(ws + WS_WLF);
    const float* BLF     = (const float*)(ws + WS_BLF);
    const float* WKEYF   = (const float*)(ws + WS_WKEYF);
    const float* WTEACHF = (const float*)(ws + WS_WTEACHF);
    const float* WROF    = (const float*)(ws + WS_WROF);
    u32*   xW  = (u32*)(ws + WS_XW);
    float* WrE = (float*)(ws + WS_WREFF);
    float* Wkt = (float*)(ws + WS_WKT);
    float* Wre = (float*)(ws + WS_WROEFF);
    const int wg = blockIdx.x, tid = threadIdx.x;
    if (wg < 512) {
        const int rb = wg >> 4, cb = wg & 15;   // 32 row-blocks x 16 col-blocks (128x64 tiles)
        const float4* xsrc = (const float4*)(XSF + (size_t)rb * 16384);
        for (int i = tid; i < 4096; i += 256) {
            float4 v = xsrc[i];
            int row = i >> 5, c4 = (i & 31) * 4;
            float* d = xls + row * 129 + c4;
            d[0] = v.x; d[1] = v.y; d[2] = v.z; d[3] = v.w;
        }
        __syncthreads();
        const int tr = tid >> 4, tc = tid & 15;
        const int c0 = cb * 64 + tc * 4;
        float acc[8][4];
#pragma unroll
        for (int rr = 0; rr < 8; ++rr) {
            acc[rr][0] = BLF[c0]; acc[rr][1] = BLF[c0 + 1];
            acc[rr][2] = BLF[c0 + 2]; acc[rr][3] = BLF[c0 + 3];
        }
        for (int k = 0; k < 128; ++k) {
            float4 w4 = *(const float4*)(WLF + (size_t)k * 1024 + c0);
#pragma unroll
            for (int rr = 0; rr < 8; ++rr) {
                float xv = xls[(tr * 8 + rr) * 129 + k];
                acc[rr][0] += xv * w4.x; acc[rr][1] += xv * w4.y;
                acc[rr][2] += xv * w4.z; acc[rr][3] += xv * w4.w;
            }
        }
#pragma unroll
        for (int rr = 0; rr < 8; ++rr) {
            size_t o = (size_t)(rb * 128 + tr * 8 + rr) * 512 + cb * 32 + tc * 2;
            u32 p0 = (u32)f2b(acc[rr][0]) | ((u32)f2b(acc[rr][1]) << 16);
            u32 p1 = (u32)f2b(acc[rr][2]) | ((u32)f2b(acc[rr][3]) << 16);
            *(uint2*)(xW + o) = make_uint2(p0, p1);
        }
    } else if (wg < 576) {
        const int m = wg - 512;
        const int c = tid * 4;
#pragma unroll
        for (int e = 0; e < 4; ++e) {
            float s = 0.f;
#pragma unroll
            for (int rr = 0; rr < 4; ++rr) s += WLF[(size_t)(128 + 4 * m + rr) * 1024 + c + e];
            WrE[m * 1024 + c + e] = s;
        }
    } else if (wg < 592) {
        const int i = (wg - 576) * 1024 + tid * 4;
#pragma unroll
        for (int e = 0; e < 4; ++e) Wkt[i + e] = WKEYF[i + e] - WTEACHF[i + e];
    } else if (wg < 600) {
        const int i = (wg - 592) * 1024 + tid * 4;
#pragma unroll
        for (int e = 0; e < 4; ++e) {
            int m = (i + e) >> 7, c = (i + e) & 127;
            float s = 0.f;
#pragma unroll
            for (int rr = 0; rr < 4; ++rr) s += WROF[(4 * m + rr) * 128 + c];
            Wre[i + e] = s;
        }
    }
}

// ---------------- main persistent kernel: 32 wgs ----------------
// 1 barrier/step (h). r is tagged dataflow published before the mem update
// (r = w@mem_old + ||w||^2 k), giving the consumer poll a full-update shadow.
// WAR safety: rT double-buffered by parity; barrier1 bounds skew <1 step.
__global__ __launch_bounds__(256, 1) void dnc_main(char* __restrict__ ws) {
    extern __shared__ char smem[];
    u16*   hr_lds = (u16*)(smem + HR_OFF);
    u16*   wfrag  = (u16*)(smem + WF_OFF);
    u16*   wkeyT  = (u16*)(smem + WK_OFF);
    float* memA   = (float*)(smem + MEM_OFF);
    float* z_lds  = (float*)(smem + Z_OFF);
    float* kv     = (float*)(smem + KV_OFF);
    float* kpart  = (float*)(smem + KP_OFF);
    float* rp     = (float*)(smem + RP_OFF);
    float* bred   = (float*)(smem + BR_OFF);
    float* wred   = (float*)(smem + WR_OFF);
    float* sc     = (float*)(smem + SC_OFF);
    float* wbF    = (float*)(smem + WB_OFF);

    const int tid  = threadIdx.x;
    const int wg   = blockIdx.x;     // col-slice id AND batch id (0..31)
    const int lane = tid & 63;
    const int wid  = tid >> 6;

    unsigned* flags = (unsigned*)(ws + WS_BAR);
    u64* rT         = (u64*)(ws + WS_RT);      // [2][32 wg][16 chunk][2 u64]
    u16* hrg        = (u16*)(ws + WS_HRG);     // [32][320] bf16 (h at +64)
    const u32*   xWP     = (const u32*)(ws + WS_XW);
    const float* WrEffF  = (const float*)(ws + WS_WREFF);
    const float* WLF     = (const float*)(ws + WS_WLF);
    const float* WKEYF   = (const float*)(ws + WS_WKEYF);
    const float* WBETAF  = (const float*)(ws + WS_WBETAF);
    const float* MEM0F   = (const float*)(ws + WS_MEM0F);
    float* HsF = (float*)(ws + WS_HS);
    float* RsF = (float*)(ws + WS_RS);

    // ---- one-time LDS init ----
    for (int i = tid; i < 32 * PADK; i += 256) hr_lds[i] = 0;   // h(-1)=0, r(-1)=0
    for (int idx = tid; idx < 10240; idx += 256) {
        int k = idx >> 5, c = idx & 31;
        int kt = k >> 5, q = (k >> 3) & 3, j = k & 7;
        int gcol = (c >> 3) * 256 + wg * 8 + (c & 7);
        float v = (k < 64) ? WrEffF[k * 1024 + gcol]
                           : WLF[(size_t)(384 + (k - 64)) * 1024 + gcol];
        wfrag[((kt * 4 + q) * 32 + c) * 8 + j] = f2b(v);
    }
    for (int i = tid; i < 256 * 64; i += 256) {   // wkeyT[m][k] = Wkey[k][m] (bf16)
        int k = i >> 6, m = i & 63;
        wkeyT[m * WKPAD + k] = f2b(WKEYF[i]);
    }
    wbF[tid] = WBETAF[tid];
    for (int i = tid; i < 256 * 64; i += 256) {   // mem state fp32
        int n = i >> 6, m = i & 63;
        memA[n * MEMPAD + m] = MEM0F[wg * 16384 + i];
    }
    __syncthreads();

    const int bt = wid & 1, ct = wid >> 1;   // MFMA tile assignment
    const int fm = lane & 15, fq = lane >> 4;
    const int pb = tid >> 3, pu = tid & 7;   // batch / slice-unit for staging & pointwise
    float c_reg = 0.f;                       // LSTM cell state for (pb, unit wg*8+pu)

    // xW gates for t=0 (packed bf16); h@Wh accumulator for t=0 is 0
    float xg0, xg1, xg2, xg3;
    {
        const size_t xb = (size_t)pb * 512 + wg * 4 + (pu >> 1);
        u32 u0 = xWP[xb], u1 = xWP[xb + 128], u2 = xWP[xb + 256], u3 = xWP[xb + 384];
        if (pu & 1) { xg0 = hi16f(u0); xg1 = hi16f(u1); xg2 = hi16f(u2); xg3 = hi16f(u3); }
        else        { xg0 = lo16f(u0); xg1 = lo16f(u1); xg2 = lo16f(u2); xg3 = lo16f(u3); }
    }
    f32x4 hWacc = {0.f, 0.f, 0.f, 0.f};

    for (int t = 0; t < T_STEPS; ++t) {
        // ================= phase A =================
        // poll r(t-1): buffer (t+1)&1, tag t. Long publish shadow -> first-try.
        {
            const u64* rch = rT + (size_t)((((t + 1) & 1) * 32 + pb) * 16 + 2 * pu) * 2;
            const u32 want = (u32)t;
            u64 v0, v1, v2, v3;
            long guard = 0;
            for (;;) {
                v0 = lda(rch); v1 = lda(rch + 1); v2 = lda(rch + 2); v3 = lda(rch + 3);
                bool ok = ((u32)v0 == want) && ((u32)(v1 >> 32) == want) &&
                          ((u32)v2 == want) && ((u32)(v3 >> 32) == want);
                if (ok) break;
                if (++guard > 2000000L) break;   // bail instead of hanging
                if (guard > 4) __builtin_amdgcn_s_sleep(1);
            }
            u32* dst = (u32*)hr_lds + pb * 164 + 4 * pu;
            dst[0] = (u32)(v0 >> 32); dst[1] = (u32)v1;
            dst[2] = (u32)(v2 >> 32); dst[3] = (u32)v3;
        }
        __syncthreads();

        // rW MFMA (kt=0,1) accumulating onto carried h@Wh
        f32x4 acc = hWacc;
#pragma unroll
        for (int kt = 0; kt < 2; ++kt) {
            short8 a = *(const short8*)(hr_lds + (bt * 16 + fm) * PADK + kt * 32 + fq * 8);
            short8 b = *(const short8*)(wfrag + ((kt * 4 + fq) * 32 + ct * 16 + fm) * 8);
            acc = __builtin_amdgcn_mfma_f32_16x16x32_bf16(a, b, acc, 0, 0, 0);
        }
#pragma unroll
        for (int r = 0; r < 4; ++r) {
            int bb = bt * 16 + fq * 4 + r;        // C/D: row = quad*4+reg
            int cc = ct * 16 + fm;                //       col = lane&15
            z_lds[bb * 36 + cc] = acc[r];
        }
        __syncthreads();

        // LSTM pointwise for hidden units [8*wg, 8*wg+8), all batches
        float hn;
        {
            float iv = z_lds[pb * 36 + pu]      + xg0;
            float fv = z_lds[pb * 36 + 8 + pu]  + xg1;
            float gv = z_lds[pb * 36 + 16 + pu] + xg2;
            float ov = z_lds[pb * 36 + 24 + pu] + xg3;
            float cn = sigm(fv) * c_reg + sigm(iv) * tanh_(gv);
            hn = sigm(ov) * tanh_(cn);
            c_reg = cn;
            HsF[(size_t)(t * BATCH + pb) * 256 + wg * 8 + pu] = hn;   // epilogue-only
        }
        // gather this batch's 8 h values via intra-wave shuffles; one lane stores 16B
        {
            u32 hbits = (u32)f2b(hn);
            int base = lane & 56;
            u32 w0 = __shfl(hbits, base + 0, 64) | (__shfl(hbits, base + 1, 64) << 16);
            u32 w1 = __shfl(hbits, base + 2, 64) | (__shfl(hbits, base + 3, 64) << 16);
            u32 w2 = __shfl(hbits, base + 4, 64) | (__shfl(hbits, base + 5, 64) << 16);
            u32 w3 = __shfl(hbits, base + 6, 64) | (__shfl(hbits, base + 7, 64) << 16);
            if ((lane & 7) == 0) {
                uint4 hv; hv.x = w0; hv.y = w1; hv.z = w2; hv.w = w3;
                st16(hrg + pb * KHR + 64 + wg * 8, hv);
            }
        }
        gridbar(flags, (unsigned)(t + 1), wg);

        // ================= phase B =================
        // issue h(t) prefetch (16 KB total), no waitcnt yet
        uint4 ha, hb4, hc, hd;
        {
            const u16* src = hrg + pb * KHR + 64 + pu * 32;
            ld16x4_issue(src, src + 8, src + 16, src + 24, ha, hb4, hc, hd);
        }
        // xW gates for t+1 (plain cached loads, drain at wait_vm0)
        {
            int tn = (t + 1 < T_STEPS) ? t + 1 : 127;
            const size_t xb = (size_t)(tn * BATCH + pb) * 512 + wg * 4 + (pu >> 1);
            u32 u0 = xWP[xb], u1 = xWP[xb + 128], u2 = xWP[xb + 256], u3 = xWP[xb + 384];
            if (pu & 1) { xg0 = hi16f(u0); xg1 = hi16f(u1); xg2 = hi16f(u2); xg3 = hi16f(u3); }
            else        { xg0 = lo16f(u0); xg1 = lo16f(u1); xg2 = lo16f(u2); xg3 = lo16f(u3); }
        }
        // h-independent work while loads fly: ||mem_n||^2 (mem_old)
        float nr2 = 0.f;
        {
            const float4* mrow = (const float4*)(memA + tid * MEMPAD);
#pragma unroll
            for (int i = 0; i < 16; ++i) {
                float4 m4 = mrow[i];
                nr2 += m4.x * m4.x + m4.y * m4.y + m4.z * m4.z + m4.w * m4.w;
            }
        }
        wait_vm0();
        {
            u16* dst = hr_lds + pb * PADK + 64 + pu * 32;
            *(uint4*)(dst)      = ha;
            *(uint4*)(dst + 8)  = hb4;
            *(uint4*)(dst + 16) = hc;
            *(uint4*)(dst + 24) = hd;
        }
        __syncthreads();

        // hW MFMA (kt=2..9) -> fresh accumulator carried to phase A of t+1
        {
            f32x4 hz = {0.f, 0.f, 0.f, 0.f};
#pragma unroll
            for (int kt = 2; kt < 10; ++kt) {
                short8 a = *(const short8*)(hr_lds + (bt * 16 + fm) * PADK + kt * 32 + fq * 8);
                short8 b = *(const short8*)(wfrag + ((kt * 4 + fq) * 32 + ct * 16 + fm) * 8);
                hz = __builtin_amdgcn_mfma_f32_16x16x32_bf16(a, b, hz, 0, 0, 0);
            }
            hWacc = hz;
        }

        // M phase: this wg owns batch b = wg; h_b in hr_lds[wg]
        const u16* hrow = hr_lds + wg * PADK + 64;
        {
            float a = 0.f;
#pragma unroll
            for (int i = 0; i < 8; ++i) {
                short8 w8 = *(const short8*)(wkeyT + lane * WKPAD + wid * 64 + i * 8);
                short8 h8 = *(const short8*)(hrow + wid * 64 + i * 8);
#pragma unroll
                for (int e = 0; e < 8; ++e)
                    a += b2f((u16)h8[e]) * b2f((u16)w8[e]);
            }
            kpart[wid * 64 + lane] = a;
        }
        {
            float bp = b2f(hrow[tid]) * wbF[tid];
#pragma unroll
            for (int off = 32; off > 0; off >>= 1) bp += __shfl_xor(bp, off, 64);
            if (lane == 0) bred[wid] = bp;
        }
        __syncthreads();
        if (tid < 64) {   // finalize k, ||k||
            float kk = kpart[tid] + kpart[64 + tid] + kpart[128 + tid] + kpart[192 + tid];
            kv[tid] = kk;
            float k2 = kk * kk;
#pragma unroll
            for (int off = 32; off > 0; off >>= 1) k2 += __shfl_xor(k2, off, 64);
            if (tid == 0) sc[1] = sqrtf(k2);
        } else if (tid == 64) {   // beta = softplus
            float zb = bred[0] + bred[1] + bred[2] + bred[3];
            sc[0] = logf(1.f + __expf(zb));
        }
        __syncthreads();
        const float beta = sc[0], knorm = sc[1];

        // num pass (nr2 precomputed): thread = mem row, on mem_old
        float num = 0.f;
        {
            const float4* mrow = (const float4*)(memA + tid * MEMPAD);
            const float4* k4p  = (const float4*)kv;
#pragma unroll
            for (int i = 0; i < 16; ++i) {
                float4 m4 = mrow[i], k4 = k4p[i];
                num += m4.x * k4.x + m4.y * k4.y + m4.z * k4.z + m4.w * k4.w;
            }
        }
        float den = fmaxf(sqrtf(nr2) * knorm, 1e-8f);
        float s   = beta * (num / den);
        // per-wave max + sumexp + sumexp^2 (fused ||w||^2), then combine
        float wm = s;
#pragma unroll
        for (int off = 32; off > 0; off >>= 1) wm = fmaxf(wm, __shfl_xor(wm, off, 64));
        float ev = __expf(s - wm);
        float wsum = ev, wsumsq = ev * ev;
#pragma unroll
        for (int off = 32; off > 0; off >>= 1) {
            wsum   += __shfl_xor(wsum, off, 64);
            wsumsq += __shfl_xor(wsumsq, off, 64);
        }
        if (lane == 0) { wred[wid] = wm; wred[4 + wid] = wsum; wred[8 + wid] = wsumsq; }
        __syncthreads();
        float gm = fmaxf(fmaxf(wred[0], wred[1]), fmaxf(wred[2], wred[3]));
        float e0 = __expf(wred[0] - gm), e1 = __expf(wred[1] - gm);
        float e2 = __expf(wred[2] - gm), e3 = __expf(wred[3] - gm);
        float gsum  = wred[4] * e0 + wred[5] * e1 + wred[6] * e2 + wred[7] * e3;
        float gsumq = wred[8] * e0 * e0 + wred[9] * e1 * e1
                    + wred[10] * e2 * e2 + wred[11] * e3 * e3;
        float w   = __expf(s - gm) / gsum;          // weight for row tid
        float wsq = gsumq / (gsum * gsum);          // ||w||^2

        // READ pass on mem_old: w lives in-wave -> shuffles
        {
            const int lm = lane & 15, q = lane >> 4;
            float r0 = 0.f, r1 = 0.f, r2 = 0.f, r3 = 0.f;
#pragma unroll
            for (int i = 0; i < 16; ++i) {
                float wn = __shfl(w, i * 4 + q, 64);
                float4 m4 = *(const float4*)(memA + (wid * 64 + i * 4 + q) * MEMPAD + 4 * lm);
                r0 += wn * m4.x; r1 += wn * m4.y; r2 += wn * m4.z; r3 += wn * m4.w;
            }
            r0 += __shfl_xor(r0, 16, 64); r0 += __shfl_xor(r0, 32, 64);
            r1 += __shfl_xor(r1, 16, 64); r1 += __shfl_xor(r1, 32, 64);
            r2 += __shfl_xor(r2, 16, 64); r2 += __shfl_xor(r2, 32, 64);
            r3 += __shfl_xor(r3, 16, 64); r3 += __shfl_xor(r3, 32, 64);
            if (q == 0) {
                rp[wid * 64 + 4 * lm + 0] = r0;
                rp[wid * 64 + 4 * lm + 1] = r1;
                rp[wid * 64 + 4 * lm + 2] = r2;
                rp[wid * 64 + 4 * lm + 3] = r3;
            }
        }
        __syncthreads();
        // tid<16: finalize 4 r-units each, publish tagged + Rs, pre-update
        if (tid < 16) {
            float rd0 = rp[4 * tid]     + rp[64 + 4 * tid]     + rp[128 + 4 * tid]     + rp[192 + 4 * tid]     + wsq * kv[4 * tid];
            float rd1 = rp[4 * tid + 1] + rp[64 + 4 * tid + 1] + rp[128 + 4 * tid + 1] + rp[192 + 4 * tid + 1] + wsq * kv[4 * tid + 1];
            float rd2 = rp[4 * tid + 2] + rp[64 + 4 * tid + 2] + rp[128 + 4 * tid + 2] + rp[192 + 4 * tid + 2] + wsq * kv[4 * tid + 2];
            float rd3 = rp[4 * tid + 3] + rp[64 + 4 * tid + 3] + rp[128 + 4 * tid + 3] + rp[192 + 4 * tid + 3] + wsq * kv[4 * tid + 3];
            u32 w0 = (u32)f2b(rd0) | ((u32)f2b(rd1) << 16);
            u32 w1 = (u32)f2b(rd2) | ((u32)f2b(rd3) << 16);
            u64* dstc = rT + (size_t)(((t & 1) * 32 + wg) * 16 + tid) * 2;
            const u64 tag = (u64)(u32)(t + 1);
            sta(dstc,     ((u64)w0 << 32) | tag);
            sta(dstc + 1, (tag << 32) | w1);
            float* rdst = RsF + (size_t)(t * BATCH + wg) * 64 + 4 * tid;   // epilogue-only
            rdst[0] = rd0; rdst[1] = rd1; rdst[2] = rd2; rdst[3] = rd3;
        }
        // mem UPDATE pass — off the critical path (covers r's flight to the LLC)
        {
            const int lm = lane & 15, q = lane >> 4;
            float4 k4 = ((const float4*)kv)[lm];
#pragma unroll
            for (int i = 0; i < 16; ++i) {
                float wn = __shfl(w, i * 4 + q, 64);
                float4* mp = (float4*)(memA + (wid * 64 + i * 4 + q) * MEMPAD + 4 * lm);
                float4 m4 = *mp;
                m4.x += wn * k4.x; m4.y += wn * k4.y; m4.z += wn * k4.z; m4.w += wn * k4.w;
                *mp = m4;
            }
        }
        // no barrier2: next step's r-poll + barrier1 bound the skew
    }
}

// ---------------- epilogue: ys = Hs@Wpre + Rs@Wro_eff + b_pre ; loss partials ----------------
__global__ void dnc_epilogue(char* __restrict__ ws, void* __restrict__ outv) {
    __shared__ float hs8[8][256];
    __shared__ float rs8[8][64];
    __shared__ float lacc;
    const float* HsF   = (const float*)(ws + WS_HS);
    const float* RsF   = (const float*)(ws + WS_RS);
    const float* WktF  = (const float*)(ws + WS_WKT);
    const float* WreF  = (const float*)(ws + WS_WROEFF);
    const float* WpreF = (const float*)(ws + WS_WPREF);
    const float* bpreF = (const float*)(ws + WS_BPREF);
    float* lossacc = (float*)(ws + WS_LOSS);
    const int bf = *(const int*)(ws + WS_FLAG);
    const int tid = threadIdx.x;
    const size_t r0 = (size_t)blockIdx.x * 8;
    if (tid == 0) lacc = 0.f;
    for (int i = tid; i < 8 * 256; i += 256) hs8[i >> 8][i & 255] = HsF[r0 * 256 + i];
    for (int i = tid; i < 8 * 64; i += 256)  rs8[i >> 6][i & 63]  = RsF[r0 * 64 + i];
    __syncthreads();
    // ys
    {
        const int rl = tid >> 5, c0 = (tid & 31) * 4;
        float a0 = bpreF[c0], a1 = bpreF[c0 + 1], a2 = bpreF[c0 + 2], a3 = bpreF[c0 + 3];
        for (int k = 0; k < 256; ++k) {
            float hv = hs8[rl][k];
            float4 w4 = *(const float4*)(WpreF + k * 128 + c0);
            a0 += hv * w4.x; a1 += hv * w4.y; a2 += hv * w4.z; a3 += hv * w4.w;
        }
        for (int m = 0; m < 64; ++m) {
            float rv = rs8[rl][m];
            float4 w4 = *(const float4*)(WreF + m * 128 + c0);
            a0 += rv * w4.x; a1 += rv * w4.y; a2 += rv * w4.z; a3 += rv * w4.w;
        }
        size_t o = (r0 + rl) * 128 + c0;
        if (bf) {
            u16* out = (u16*)outv;
            out[o] = f2b(a0); out[o + 1] = f2b(a1); out[o + 2] = f2b(a2); out[o + 3] = f2b(a3);
        } else {
            float* out = (float*)outv;
            out[o] = a0; out[o + 1] = a1; out[o + 2] = a2; out[o + 3] = a3;
        }
    }
    // loss: sum (h @ (Wkey - Wteach))^2
    {
        const int rl = tid >> 5, m0 = (tid & 31) * 2;
        float d0 = 0.f, d1 = 0.f;
        for (int k = 0; k < 256; ++k) {
            float hv = hs8[rl][k];
            d0 += hv * WktF[k * 64 + m0];
            d1 += hv * WktF[k * 64 + m0 + 1];
        }
        float p = d0 * d0 + d1 * d1;
#pragma unroll
        for (int off = 32; off > 0; off >>= 1) p += __shfl_xor(p, off, 64);
        if ((tid & 63) == 0) atomicAdd(&lacc, p);
        __syncthreads();
        if (tid == 0) atomicAdd(lossacc, lacc);
    }
}

__global__ void dnc_loss_fin(const char* __restrict__ ws, void* __restrict__ outv) {
    if (threadIdx.x == 0 && blockIdx.x == 0) {
        float l = *(const float*)(ws + WS_LOSS) * (1.f / 2048.f);
        if (*(const int*)(ws + WS_FLAG)) ((u16*)outv)[524288] = f2b(l);
        else                             ((float*)outv)[524288] = l;
    }
}

// ---------------- launch ----------------
extern "C" void kernel_launch(void* const* d_in, const int* in_sizes, int n_in,
                              void* d_out, int out_size, void* d_ws, size_t ws_size,
                              hipStream_t stream) {
    char* ws = (char*)d_ws;
    hipMemsetAsync(d_ws, 0, WS_ZSET, stream);   // flags, rT tags, loss, dtype flag, hrg
    dnc_normalize<<<512, 256, 0, stream>>>(d_in[0], d_in[1], d_in[2], d_in[3], d_in[4],
                                           d_in[5], d_in[6], d_in[7], d_in[8], d_in[9], ws);
    (void)hipFuncSetAttribute((const void*)dnc_prologue,
                              hipFuncAttributeMaxDynamicSharedMemorySize, 128 * 129 * 4);
    dnc_prologue<<<600, 256, 128 * 129 * 4, stream>>>(ws);
    (void)hipFuncSetAttribute((const void*)dnc_main,
                              hipFuncAttributeMaxDynamicSharedMemorySize, LDS_TOTAL);
    dnc_main<<<32, 256, LDS_TOTAL, stream>>>(ws);
    dnc_epilogue<<<512, 256, 0, stream>>>(ws, d_out);
    dnc_loss_fin<<<1, 64, 0, stream>>>(ws, d_out);
}